// Round 10
// baseline (129.693 us; speedup 1.0000x reference)
//
#include <hip/hip_runtime.h>
#include <stdint.h>

typedef int   int4v  __attribute__((ext_vector_type(4)));
typedef int   int8v  __attribute__((ext_vector_type(8)));
typedef float floatx4 __attribute__((ext_vector_type(4)));
typedef float float16v __attribute__((ext_vector_type(16)));

#define BIAS 128.0f

// async global->LDS DMA, 16 B per lane; LDS dest = wave-uniform base + lane*16
__device__ __forceinline__ void gload_lds16(const void* g, void* l) {
    __builtin_amdgcn_global_load_lds(
        (const __attribute__((address_space(1))) unsigned int*)g,
        (__attribute__((address_space(3))) unsigned int*)l, 16, 0, 0);
}

// ---------------- kernel 0: W -> fp8(-4096*w) in 32x32x64 B-frag order + zero loss.
// Layout: tile T (codes 32T..32T+31), half q (k-bytes q*16..+15 of each 32-k group), lane l:
//   byte = T*2048 + q*1024 + l*16 + p ;  c = 32T+(l&31), k = (l>>5)*32 + q*16 + p
__global__ void vq_prep(const float* __restrict__ W, unsigned char* __restrict__ Wsw,
                        float* __restrict__ out0) {
    const int s = blockIdx.x * 256 + threadIdx.x;   // 16384 slots of 16 B
    const int T = s >> 7;
    const int q = (s >> 6) & 1;
    const int l = s & 63;
    const int c  = T * 32 + (l & 31);
    const int kb = (l >> 5) * 32 + q * 16;
    const floatx4* wp = (const floatx4*)(W + c * 64 + kb);
    int4v d;
    #pragma unroll
    for (int i = 0; i < 4; ++i) {
        floatx4 f = wp[i];
        int w_ = __builtin_amdgcn_cvt_pk_fp8_f32(f[0] * -4096.0f, f[1] * -4096.0f, 0, false);
        w_ = __builtin_amdgcn_cvt_pk_fp8_f32(f[2] * -4096.0f, f[3] * -4096.0f, w_, true);
        d[i] = w_;
    }
    ((int4v*)Wsw)[s] = d;
    if (s == 0) *out0 = 0.0f;
}

// ---------------- kernel 1: block = 4 waves x 64 rows = 256 rows, x 512 codes (32 KB LDS).
// Wave = 2 M-tiles of 32 rows; each b-tile read feeds 2 MFMAs. No K-loop barriers.
// Per-row packed min scatter-written to minidx2[cg][row] (no atomics).
__launch_bounds__(256)
__attribute__((amdgpu_waves_per_eu(4, 4)))
__global__ void vq_main(const float* __restrict__ z, const unsigned char* __restrict__ Wsw,
                        unsigned int* __restrict__ minidx2) {
    __shared__ __align__(16) unsigned char B[32768];

    const int tid  = threadIdx.x;
    const int lane = tid & 63;
    const int wave = tid >> 6;          // 0..3
    const int cg     = blockIdx.x & 7;  // code group (512 codes)
    const int rowblk = blockIdx.x >> 3; // 0..255 (256 rows each)
    const int l31 = lane & 31;
    const int lh  = lane >> 5;

    // ---- stage this cg's 32 KB of B once (async DMA, linear copy)
    #pragma unroll
    for (int i = 0; i < 8; ++i) {
        const int off = wave * 8192 + i * 1024 + lane * 16;
        gload_lds16(Wsw + cg * 32768 + off, B + off);
    }

    // ---- A fragments: 2 M-tiles of 32 rows; lane: row = l&31, k = (l>>5)*32 + j
    const int rowwave = rowblk * 256 + wave * 64;
    int8v afrag[2];
    #pragma unroll
    for (int mt = 0; mt < 2; ++mt) {
        const floatx4* zp = (const floatx4*)(z + (rowwave + mt * 32 + l31) * 64 + lh * 32);
        #pragma unroll
        for (int d = 0; d < 8; ++d) {
            floatx4 v = zp[d];
            int w_ = __builtin_amdgcn_cvt_pk_fp8_f32(v[0], v[1], 0, false);
            w_ = __builtin_amdgcn_cvt_pk_fp8_f32(v[2], v[3], w_, true);
            afrag[mt][d] = w_;
        }
    }

    float16v bias;
    #pragma unroll
    for (int i = 0; i < 16; ++i) bias[i] = BIAS;

    unsigned int minpk[2][16];
    #pragma unroll
    for (int mt = 0; mt < 2; ++mt)
        #pragma unroll
        for (int r = 0; r < 16; ++r) minpk[mt][r] = 0xFFFFFFFFu;

    __syncthreads();    // B staged (drains DMA)

    // ---- K loop: 16 tiles of 32 codes from LDS; 2 MFMAs (K=64) per b-tile
    const unsigned int kk0 = (unsigned int)(cg * 512 + l31);
    #pragma unroll 1
    for (int t = 0; t < 16; ++t) {
        int8v b;
        *(int4v*)&b       = *(const int4v*)(B + t * 2048 + lane * 16);
        *((int4v*)&b + 1) = *(const int4v*)(B + t * 2048 + 1024 + lane * 16);
        const unsigned int kk = kk0 + (unsigned int)(t * 32);
        #pragma unroll
        for (int mt = 0; mt < 2; ++mt) {
            float16v acc = __builtin_amdgcn_mfma_scale_f32_32x32x64_f8f6f4(
                afrag[mt], b, bias, 0, 0, 0, 0x7F7F7F7F, 0, 0x7F7F7F7F);
            #pragma unroll
            for (int r = 0; r < 16; ++r) {
                unsigned int p = __float_as_uint(acc[r]) | kk;   // monotone pack
                minpk[mt][r] = p < minpk[mt][r] ? p : minpk[mt][r];
            }
        }
    }

    // ---- butterfly allreduce over the 32 code-columns, scatter per-row min.
    // D layout (32x32): col = lane&31, row = (r&3) + 8*(r>>2) + 4*(lane>>5)
    unsigned int* mrow = minidx2 + cg * 65536;
    #pragma unroll
    for (int mt = 0; mt < 2; ++mt)
        #pragma unroll
        for (int r = 0; r < 16; ++r) {
            unsigned int v = minpk[mt][r];
            #pragma unroll
            for (int m = 1; m < 32; m <<= 1) {
                unsigned int o = (unsigned int)__shfl_xor((int)v, m, 64);
                v = o < v ? o : v;
            }
            if (l31 == r) {
                const int row = rowwave + mt * 32 + (r & 3) + 8 * (r >> 2) + 4 * lh;
                mrow[row] = v;
            }
        }
}

// ---------------- kernel 2: reduce 8 candidates/row, gather W[idx], write z_q, loss
__launch_bounds__(256)
__global__ void vq_out(const float* __restrict__ z, const float* __restrict__ W,
                       const unsigned int* __restrict__ minidx2, float* __restrict__ out) {
    __shared__ float ls[4];
    const int g = blockIdx.x * 256 + threadIdx.x;   // 262144 = rows*4
    const int row = g >> 2;
    const int seg = g & 3;                          // 16-float segment

    unsigned int m0 = minidx2[row];
    #pragma unroll
    for (int c = 1; c < 8; ++c) {
        unsigned int mc = minidx2[c * 65536 + row];
        m0 = mc < m0 ? mc : m0;
    }
    const unsigned int idx = m0 & 0xFFFu;

    const floatx4* wp = (const floatx4*)(W + idx * 64 + seg * 16);
    const floatx4* zp = (const floatx4*)(z + row * 64 + seg * 16);
    floatx4* op = (floatx4*)(out + 1 + row * 64 + seg * 16);
    float loss = 0.0f;
    #pragma unroll
    for (int p2 = 0; p2 < 4; ++p2) {
        floatx4 wv = wp[p2];
        floatx4 zv = zp[p2];
        op[p2] = wv;
        #pragma unroll
        for (int j = 0; j < 4; ++j) {
            float d = zv[j] - wv[j];
            loss = fmaf(d, d, loss);
        }
    }
    #pragma unroll
    for (int m = 1; m < 64; m <<= 1) loss += __shfl_xor(loss, m, 64);
    const int lane = threadIdx.x & 63, wave = threadIdx.x >> 6;
    if (lane == 0) ls[wave] = loss;
    __syncthreads();
    if (threadIdx.x == 0) {
        float t = (ls[0] + ls[1]) + (ls[2] + ls[3]);
        atomicAdd(out, t * (0.25f / 4194304.0f));
    }
}

extern "C" void kernel_launch(void* const* d_in, const int* in_sizes, int n_in,
                              void* d_out, int out_size, void* d_ws, size_t ws_size,
                              hipStream_t stream) {
    (void)in_sizes; (void)n_in; (void)out_size; (void)ws_size;
    const float* z = (const float*)d_in[0];
    const float* W = (const float*)d_in[1];
    unsigned char* Wsw = (unsigned char*)d_ws;                       // 256 KB fp8 table
    unsigned int* minidx2 = (unsigned int*)((char*)d_ws + 262144);   // 2 MB: [cg][row]
    float* out = (float*)d_out;

    vq_prep<<<64, 256, 0, stream>>>(W, Wsw, out);
    vq_main<<<2048, 256, 0, stream>>>(z, Wsw, minidx2);
    vq_out<<<1024, 256, 0, stream>>>(z, W, minidx2, out);
}